// Round 3
// baseline (251.007 us; speedup 1.0000x reference)
//
#include <hip/hip_runtime.h>
#include <hip/hip_fp16.h>

// Dtypes (established R0-R3): x, W*, b* = f32; edge_index runtime-detected i64/i32;
// output f32.
// R16 post-mortem: planar fp8 split REGRESSED (258.7): agg VALUBusy 75%, hbm 11%
// -> latency-ish, and split doubled per-edge work.
// R17 post-mortem (219.9): fp16 staging + pk-add only -5us -> agg is
// LATENCY x CONCURRENCY bound (decode VALU was filling stalls). FETCH 35MB vs
// 6.4MB table = per-XCD L2 thrash at L3 latency; serial tail rounds dominate.
// R18 (this round):
//  1) part+build replaced by direct global-atomic CSR scatter (order was already
//     nondeterministic; sum order-independent up to fp16 rounding).
//  2) aggs restructured to ONE predicated gather sweep (32 edges preloaded idx,
//     branchless mask-to-zero, own-row clamp for inactive) -> 1 idx round +
//     1 gather round per wave instead of 2-4 serial rounds. deg>32 rare path.

typedef _Float16 half8 __attribute__((ext_vector_type(8)));
typedef float f32x4 __attribute__((ext_vector_type(4)));

constexpr int CAP = 64;       // per-node CSR capacity (max in-degree ~42)

__device__ inline __half2 h2u(unsigned int u) {
    union { unsigned int x; __half2 h; } c;
    c.x = u;
    return c.h;
}
__device__ inline unsigned int u_h2(__half2 h) {
    union { __half2 h; unsigned int x; } c;
    c.h = h;
    return c.x;
}

__device__ inline unsigned int u4c(uint4 p, int j) {  // j compile-time after unroll
    return (j & 2) ? ((j & 1) ? p.w : p.z) : ((j & 1) ? p.y : p.x);
}

// all blocks: grid-stride zero cnt. block 0: detect edge_index width
// (flags[4]: 0 => i64). blocks 1..: W -> Wt fp16 transpose.
__global__ __launch_bounds__(256) void prep_kernel(const int* __restrict__ ei, int twoE,
                                                   int* __restrict__ flags,
                                                   int* __restrict__ cnt, int n,
                                                   const float* __restrict__ W1,
                                                   const float* __restrict__ W2,
                                                   const float* __restrict__ W3,
                                                   __half* __restrict__ Wt1,
                                                   __half* __restrict__ Wt2,
                                                   __half* __restrict__ Wt3) {
    for (int i = blockIdx.x * 256 + threadIdx.x; i < n; i += gridDim.x * 256) cnt[i] = 0;
    if (blockIdx.x == 0) {
        if (threadIdx.x < 8) flags[threadIdx.x] = 0;
        __syncthreads();
        int c = 0;
        for (int j = threadIdx.x; j < 2048 && j < twoE; j += 256) {
            if ((j & 1) && ei[j] != 0) c++;   // i64 values <2^31: zero high words
        }
        if (c) atomicAdd(&flags[4], c);
        return;
    }
    int i = (blockIdx.x - 1) * 256 + threadIdx.x;
    if (i < 128 * 96) {
        int f = i / 128, k = i - f * 128;
        Wt1[i] = __float2half(W1[(size_t)k * 96 + f]);
    } else if (i < 128 * 96 + 96 * 96) {
        int j = i - 128 * 96;
        int f = j / 96, k = j - f * 96;
        Wt2[j] = __float2half(W2[(size_t)k * 96 + f]);
    } else if (i < 128 * 96 + 96 * 96 + 96 * 32) {
        int j = i - 128 * 96 - 96 * 96;
        int f = j / 96, k = j - f * 96;
        Wt3[j] = __float2half(W3[(size_t)k * 32 + f]);
    }
}

__device__ inline int ld_idx(const int* ei, int half_, int i, int E, bool i64) {
    return i64 ? ei[2 * (half_ * (size_t)E + i)] : ei[half_ * (size_t)E + i];
}

// Direct CSR build: 2 edges/thread, vectorized index loads, global atomicAdd
// slot reservation. Row order nondeterministic (was already, via old atomics).
__global__ __launch_bounds__(256) void scatter_kernel(const int* __restrict__ ei,
                                                      const int* __restrict__ flags,
                                                      int* __restrict__ cnt,
                                                      unsigned short* __restrict__ csr,
                                                      int E, int n) {
    const bool i64 = (flags[4] == 0);
    const int t = blockIdx.x * 256 + threadIdx.x;
    const int i0 = t * 2;
    if (i0 >= E) return;
    int s0, s1 = -1, d0, d1 = -1;
    if (i0 + 1 < E) {
        if (i64) {
            int4 sv = ((const int4*)ei)[t];                       // src pair (lo words x,z)
            int4 dv = ((const int4*)(ei + 2 * (size_t)E))[t];     // dst pair
            s0 = sv.x; s1 = sv.z; d0 = dv.x; d1 = dv.z;
        } else {
            int2 sv = ((const int2*)ei)[t];
            int2 dv = ((const int2*)(ei + (size_t)E))[t];
            s0 = sv.x; s1 = sv.y; d0 = dv.x; d1 = dv.y;
        }
    } else {
        s0 = ld_idx(ei, 0, i0, E, i64);
        d0 = ld_idx(ei, 1, i0, E, i64);
    }
    if ((unsigned)s0 < (unsigned)n && (unsigned)d0 < (unsigned)n) {
        int p = atomicAdd(&cnt[d0], 1);
        if (p < CAP) csr[(size_t)d0 * CAP + p] = (unsigned short)s0;
    }
    if (s1 >= 0 && (unsigned)s1 < (unsigned)n && (unsigned)d1 < (unsigned)n) {
        int p = atomicAdd(&cnt[d1], 1);
        if (p < CAP) csr[(size_t)d1 * CAP + p] = (unsigned short)s1;
    }
}

__device__ inline half8 to_h8(float4 u0, float4 u1) {
    half8 r;
    r[0] = (_Float16)u0.x; r[1] = (_Float16)u0.y; r[2] = (_Float16)u0.z; r[3] = (_Float16)u0.w;
    r[4] = (_Float16)u1.x; r[5] = (_Float16)u1.y; r[6] = (_Float16)u1.z; r[7] = (_Float16)u1.w;
    return r;
}

// out[n,f] = dinv[n] * sum_k X[n,k]*W[k,f], fp16 out (row stride F).
template <int K, int F, bool XF32>
__global__ __launch_bounds__(256) void gemm_mfma(const void* __restrict__ X,
                                                 const __half* __restrict__ Wt,
                                                 const int* __restrict__ cnt,
                                                 __half* __restrict__ out, int n) {
    constexpr int KP = K + 8;
    constexpr int FT = F / 16;
    constexpr int KC = K / 32;
    __shared__ _Float16 Wl[F * KP];
    for (int i = threadIdx.x; i < F * (K / 8); i += 256) {
        int f = i / (K / 8), c = i - f * (K / 8);
        *(half8*)&Wl[f * KP + c * 8] = *(const half8*)&Wt[(size_t)f * K + c * 8];
    }
    __syncthreads();
    const int wave = threadIdx.x >> 6, lane = threadIdx.x & 63;
    const int node0 = (blockIdx.x * 4 + wave) * 16;
    if (node0 >= n) return;
    const int m = lane & 15, q = lane >> 4;
    const int arow = min(node0 + m, n - 1);

    half8 af[KC];
    if (XF32) {
        const float* xp = (const float*)X + (size_t)arow * K + q * 8;
#pragma unroll
        for (int kc = 0; kc < KC; kc++) {
            float4 u0 = *(const float4*)(xp + kc * 32);
            float4 u1 = *(const float4*)(xp + kc * 32 + 4);
            af[kc] = to_h8(u0, u1);
        }
    } else {
        const __half* xp = (const __half*)X + (size_t)arow * K + q * 8;
#pragma unroll
        for (int kc = 0; kc < KC; kc++) af[kc] = *(const half8*)(xp + kc * 32);
    }

    f32x4 acc[FT];
#pragma unroll
    for (int t = 0; t < FT; t++) acc[t] = (f32x4)0.f;
#pragma unroll
    for (int kc = 0; kc < KC; kc++) {
#pragma unroll
        for (int t = 0; t < FT; t++) {
            half8 b = *(const half8*)&Wl[(t * 16 + m) * KP + kc * 32 + q * 8];
            acc[t] = __builtin_amdgcn_mfma_f32_16x16x32_f16(af[kc], b, acc[t], 0, 0, 0);
        }
    }
    float dv[4];
#pragma unroll
    for (int r = 0; r < 4; r++) {
        int node = node0 + q * 4 + r;
        dv[r] = (node < n) ? rsqrtf(1.0f + (float)cnt[node]) : 0.f;
    }
#pragma unroll
    for (int t = 0; t < FT; t++)
#pragma unroll
        for (int r = 0; r < 4; r++) {
            int node = node0 + q * 4 + r;
            if (node < n) {
                float vv = acc[t][r] * dv[r];
                out[(size_t)node * F + t * 16 + m] = __float2half(vv);
            }
        }
}

// agg F=96 fp16. One node/wave; lanes 0-23 edge-group 0, 24-47 group 1 (2
// edges/instr); shfl(+24) combine. Single predicated gather sweep of 32 edges
// with preloaded indices; invalid slots clamp to own row (L1-hot) and mask to
// +0 before pk-add. deg>32 rare serial path.
__global__ __launch_bounds__(256) void agg96_f16(const __half* __restrict__ xws,
                                                 const int* __restrict__ cnt,
                                                 const unsigned short* __restrict__ csr,
                                                 const float* __restrict__ bias,
                                                 __half* __restrict__ out, int n) {
    int node = blockIdx.x * 4 + (threadIdx.x >> 6);
    int lane = threadIdx.x & 63;
    if (node >= n) return;
    const int g = lane < 24 ? 0 : 1;
    const int c = g ? lane - 24 : lane;
    const bool act = lane < 48;
    const int cc = act ? c : 0;          // keep masked gathers in-row
    const uint4* r4 = (const uint4*)(csr + (size_t)node * CAP);  // 128B-aligned
    const unsigned int* r2 = (const unsigned int*)r4;
    uint4 P0 = r4[0], P1 = r4[1], P2 = r4[2], P3 = r4[3];        // idx for edges 0..31
    int deg = cnt[node];
    int m = min(deg, CAP);
    const int mm = min(m, 32);
    float dv = rsqrtf(1.0f + (float)deg);
    __half2 a0 = h2u(0u), a1 = h2u(0u);   // features c*4 .. c*4+3
    if (lane < 24) {
        uint2 s = *(const uint2*)(xws + (size_t)node * 96 + c * 4);
        a0 = h2u(s.x);
        a1 = h2u(s.y);
    }
    const int gs = g * 16;
#pragma unroll
    for (int j = 0; j < 16; j++) {
        unsigned int word = (j < 4) ? u4c(P0, j) :
                            (j < 8) ? u4c(P1, j - 4) :
                            (j < 12) ? u4c(P2, j - 8) : u4c(P3, j - 12);
        bool sel = act && (2 * j + g) < mm;
        int u = sel ? (int)((word >> gs) & 0xFFFFu) : node;
        uint2 w = *(const uint2*)(xws + (size_t)u * 96 + cc * 4);
        a0 = __hadd2(a0, h2u(sel ? w.x : 0u));
        a1 = __hadd2(a1, h2u(sel ? w.y : 0u));
    }
    for (int e = 32; e < m; e += 2) {     // rare (P(deg>32) ~ 1e-3)
        unsigned int pw = r2[e >> 1];
        if (act && (e + g) < m) {
            int u = (int)((pw >> gs) & 0xFFFFu);
            uint2 w = *(const uint2*)(xws + (size_t)u * 96 + cc * 4);
            a0 = __hadd2(a0, h2u(w.x));
            a1 = __hadd2(a1, h2u(w.y));
        }
    }
    unsigned int p0 = __shfl((int)u_h2(a0), lane + 24);
    unsigned int p1 = __shfl((int)u_h2(a1), lane + 24);
    if (lane < 24) {
        a0 = __hadd2(a0, h2u(p0));
        a1 = __hadd2(a1, h2u(p1));
        float2 f0 = __half22float2(a0);
        float2 f1 = __half22float2(a1);
        float4 bb = *(const float4*)&bias[c * 4];
        float r0 = fmaxf(fmaf(dv, f0.x, bb.x), 0.f);
        float r1 = fmaxf(fmaf(dv, f0.y, bb.y), 0.f);
        float r2v = fmaxf(fmaf(dv, f1.x, bb.z), 0.f);
        float r3 = fmaxf(fmaf(dv, f1.y, bb.w), 0.f);
        union { __half2 h[2]; uint2 u; } pk;
        pk.h[0] = __floats2half2_rn(r0, r1);
        pk.h[1] = __floats2half2_rn(r2v, r3);
        *(uint2*)(out + (size_t)node * 96 + c * 4) = pk.u;
    }
}

// agg F=32 (fp16) + log_softmax. 4 x 16-lane groups = 4 edges/instr, single
// predicated sweep of 32 edges, butterfly combine; f32 out.
__global__ __launch_bounds__(256) void agg32_lsm(const __half* __restrict__ xws,
                                                 const int* __restrict__ cnt,
                                                 const unsigned short* __restrict__ csr,
                                                 const float* __restrict__ bias,
                                                 float* __restrict__ out, int n) {
    int node = blockIdx.x * 4 + (threadIdx.x >> 6);
    int lane = threadIdx.x & 63;
    if (node >= n) return;
    const int g = lane >> 4, l = lane & 15;
    const uint4* r4 = (const uint4*)(csr + (size_t)node * CAP);
    const unsigned int* r2 = (const unsigned int*)r4;
    uint4 P0 = r4[0], P1 = r4[1], P2 = r4[2], P3 = r4[3];
    int deg = cnt[node];
    int m = min(deg, CAP);
    const int mm = min(m, 32);
    float dv = rsqrtf(1.0f + (float)deg);
    __half2 a = h2u(0u);
    if (g == 0) a = *(const __half2*)(xws + (size_t)node * 32 + l * 2);
    const int gs = (g & 1) * 16;
    const int ghi = g >> 1;
#pragma unroll
    for (int j = 0; j < 8; j++) {
        uint4 P = (j < 2) ? P0 : (j < 4) ? P1 : (j < 6) ? P2 : P3;
        unsigned int wA = u4c(P, (2 * j) & 3);
        unsigned int wB = u4c(P, (2 * j + 1) & 3);
        unsigned int word = ghi ? wB : wA;
        bool sel = (4 * j + g) < mm;
        int u = sel ? (int)((word >> gs) & 0xFFFFu) : node;
        __half2 f = *(const __half2*)(xws + (size_t)u * 32 + l * 2);
        a = __hadd2(a, sel ? f : h2u(0u));
    }
    for (int e = 32; e < m; e += 4) {     // rare
        unsigned int w0 = r2[e >> 1], w1 = r2[(e >> 1) + 1];
        if ((e + g) < m) {
            unsigned int word = ghi ? w1 : w0;
            int u = (int)((word >> gs) & 0xFFFFu);
            a = __hadd2(a, *(const __half2*)(xws + (size_t)u * 32 + l * 2));
        }
    }
    a = __hadd2(a, h2u((unsigned int)__shfl_xor((int)u_h2(a), 16)));
    a = __hadd2(a, h2u((unsigned int)__shfl_xor((int)u_h2(a), 32)));
    if (g == 0) {
        float2 av = __half22float2(a);
        float2 b = *(const float2*)&bias[l * 2];
        float rx = fmaf(dv, av.x, b.x), ry = fmaf(dv, av.y, b.y);
        float mx = fmaxf(rx, ry);
        mx = fmaxf(mx, __shfl_xor(mx, 1));
        mx = fmaxf(mx, __shfl_xor(mx, 2));
        mx = fmaxf(mx, __shfl_xor(mx, 4));
        mx = fmaxf(mx, __shfl_xor(mx, 8));
        float s = expf(rx - mx) + expf(ry - mx);
        s += __shfl_xor(s, 1);
        s += __shfl_xor(s, 2);
        s += __shfl_xor(s, 4);
        s += __shfl_xor(s, 8);
        float ls = logf(s);
        ((float2*)out)[(size_t)node * 16 + l] = {rx - mx - ls, ry - mx - ls};
    }
}

extern "C" void kernel_launch(void* const* d_in, const int* in_sizes, int n_in,
                              void* d_out, int out_size, void* d_ws, size_t ws_size,
                              hipStream_t stream) {
    const float* x  = (const float*)d_in[0];
    const int*   ei = (const int*)d_in[1];
    const float* W1 = (const float*)d_in[2];
    const float* b1 = (const float*)d_in[3];
    const float* W2 = (const float*)d_in[4];
    const float* b2 = (const float*)d_in[5];
    const float* W3 = (const float*)d_in[6];
    const float* b3 = (const float*)d_in[7];
    float* out = (float*)d_out;

    const int N_ = in_sizes[0] / 128;   // 50000
    const int E_ = in_sizes[1] / 2;     // 800000

    char* base = (char*)d_ws;
    size_t off = 0;
    auto take = [&](size_t bytes) {
        void* p = base + off;
        off = (off + bytes + 255) & ~(size_t)255;
        return p;
    };
    int*    flags   = (int*)take(4 * 8);
    int*    cnt     = (int*)take(4 * (size_t)N_);
    unsigned short* csr = (unsigned short*)take(2 * (size_t)N_ * CAP);
    __half* Wt1     = (__half*)take(2 * 128 * 96);
    __half* Wt2     = (__half*)take(2 * 96 * 96);
    __half* Wt3     = (__half*)take(2 * 96 * 32);
    __half* bufA    = (__half*)take(2 * (size_t)N_ * 96);   // fp16 activations A
    __half* bufB    = (__half*)take(2 * (size_t)N_ * 96);   // fp16 activations B

    const int prepBlocks = 1 + (128 * 96 + 96 * 96 + 96 * 32 + 255) / 256;
    prep_kernel<<<prepBlocks, 256, 0, stream>>>(ei, in_sizes[1], flags, cnt, N_,
                                                W1, W2, W3, Wt1, Wt2, Wt3);
    scatter_kernel<<<(E_ + 511) / 512, 256, 0, stream>>>(ei, flags, cnt, csr, E_, N_);

    const int gGemm = (N_ + 63) / 64;
    const int gAgg  = (N_ + 3) / 4;

    gemm_mfma<128, 96, true><<<gGemm, 256, 0, stream>>>(x, Wt1, cnt, bufA, N_);
    agg96_f16<<<gAgg, 256, 0, stream>>>(bufA, cnt, csr, b1, bufB, N_);
    gemm_mfma<96, 96, false><<<gGemm, 256, 0, stream>>>(bufB, Wt2, cnt, bufA, N_);
    agg96_f16<<<gAgg, 256, 0, stream>>>(bufA, cnt, csr, b2, bufB, N_);
    gemm_mfma<96, 32, false><<<gGemm, 256, 0, stream>>>(bufB, Wt3, cnt, bufA, N_);
    agg32_lsm<<<gAgg, 256, 0, stream>>>(bufA, cnt, csr, b3, out, N_);
}

// Round 4
// 210.578 us; speedup vs baseline: 1.1920x; 1.1920x over previous
//
#include <hip/hip_runtime.h>
#include <hip/hip_fp16.h>

// Dtypes (established R0-R3): x, W*, b* = f32; edge_index runtime-detected i64/i32;
// output f32.
// R16 post-mortem (258.7): fp8 planar split regressed; agg was VALU-bound on the
// bit-twiddle fp8 decode (~28 VALU/4feats), VALUBusy 75%, hbm 11%.
// R17 (219.9, BEST): fp16 staging + pk-add. Aggs ~40us each: VALU floor ~10us ->
// ~75% memory stall; 9.6MB fp16 table >> 4MB per-XCD L2 (random gather misses).
// R18 post-mortem (251.0): global-atomic scatter CSR = 60-65us (latency-serial,
// VALUBusy 0.5%) — reverted. Predicated sweep aggs = neutral — tail rounds are
// not the agg bottleneck.
// R19 (this round):
//  1) restore part+build CSR; EPB 4096->2048 (196->391 blocks, 1.5/CU).
//  2) fp8 staging via NATIVE gfx950 codec (v_cvt_pk_f32_fp8 / v_cvt_pk_fp8_f32,
//     OCP e4m3): fp8's 4.8MB L2-resident table + only ~6 VALU/4feats decode.
//     f32 accumulate. Layer-3 table stays fp16 (3.2MB fits L2). absmax evidence:
//     fp8 vs fp16 staging gave identical absmax (2^-6) in R15/R17 -> fp8 free.

typedef _Float16 half8 __attribute__((ext_vector_type(8)));
typedef float f32x4 __attribute__((ext_vector_type(4)));
typedef float f32x2 __attribute__((ext_vector_type(2)));

constexpr int CAP = 64;       // per-node CSR capacity (max in-degree ~42)
constexpr int NPB = 128;      // nodes per bin
constexpr int NBINS_P = 512;  // padded bin count (true bins = 391)
constexpr int EPB = 2048;     // edges per partition block (R19: was 4096)
constexpr int BCAP = 2560;    // per-bin edge capacity

__device__ inline __half2 h2u(unsigned int u) {
    union { unsigned int x; __half2 h; } c;
    c.x = u;
    return c.h;
}
__device__ inline unsigned int u_h2(__half2 h) {
    union { __half2 h; unsigned int x; } c;
    c.h = h;
    return c.x;
}

// ---- fp8 e4m3 codec: native gfx950 HW converts, exact bit-twiddle fallback ----
__device__ inline unsigned char f_to_fp8(float f) {
#if __has_builtin(__builtin_amdgcn_cvt_pk_fp8_f32)
    return (unsigned char)(__builtin_amdgcn_cvt_pk_fp8_f32(f, f, 0, false) & 0xFF);
#else
    f = fminf(fmaxf(f, -448.0f), 448.0f);
    unsigned short u = __half_as_ushort(__float2half(f * 0.00390625f));
    unsigned short mag = (unsigned short)((u & 0x7FFF) + 0x40);  // RNE bias, carry ok
    return (unsigned char)(((u >> 8) & 0x80) | (mag >> 7));
#endif
}

__device__ inline float4 fp8x4_to_f4(unsigned int w) {
#if __has_builtin(__builtin_amdgcn_cvt_pk_f32_fp8)
    f32x2 lo = __builtin_amdgcn_cvt_pk_f32_fp8(w, false);
    f32x2 hi = __builtin_amdgcn_cvt_pk_f32_fp8(w, true);
    return {lo[0], lo[1], hi[0], hi[1]};
#else
    // exact: build half with exp field biased -8, multiply by 256
    unsigned int lo = ((w << 7) & 0x3F80u) | ((w << 8) & 0x8000u);
    unsigned int hi = ((w >> 1) & 0x3F80u) | (w & 0x8000u);
    union { unsigned int u; __half2 h; } cv;
    cv.u = lo | (hi << 16);
    float2 a = __half22float2(cv.h);
    unsigned int lo2 = ((w >> 9) & 0x3F80u) | ((w >> 8) & 0x8000u);
    unsigned int hi2 = ((w >> 17) & 0x3F80u) | ((w >> 16) & 0x8000u);
    cv.u = lo2 | (hi2 << 16);
    float2 b = __half22float2(cv.h);
    return {a.x * 256.f, a.y * 256.f, b.x * 256.f, b.y * 256.f};
#endif
}

// block 0: detect edge_index width (flags[4]: 0 => i64) + zero bin_cnt;
// blocks 1..: W -> Wt fp16
__global__ __launch_bounds__(256) void prep_kernel(const int* __restrict__ ei, int twoE,
                                                   int* __restrict__ flags,
                                                   int* __restrict__ bin_cnt,
                                                   const float* __restrict__ W1,
                                                   const float* __restrict__ W2,
                                                   const float* __restrict__ W3,
                                                   __half* __restrict__ Wt1,
                                                   __half* __restrict__ Wt2,
                                                   __half* __restrict__ Wt3) {
    if (blockIdx.x == 0) {
        if (threadIdx.x < 8) flags[threadIdx.x] = 0;
        for (int b = threadIdx.x; b < NBINS_P; b += 256) bin_cnt[b] = 0;
        __syncthreads();
        int c = 0;
        for (int j = threadIdx.x; j < 2048 && j < twoE; j += 256) {
            if ((j & 1) && ei[j] != 0) c++;   // i64 values <2^31: zero high words
        }
        if (c) atomicAdd(&flags[4], c);
        return;
    }
    int i = (blockIdx.x - 1) * 256 + threadIdx.x;
    if (i < 128 * 96) {
        int f = i / 128, k = i - f * 128;
        Wt1[i] = __float2half(W1[(size_t)k * 96 + f]);
    } else if (i < 128 * 96 + 96 * 96) {
        int j = i - 128 * 96;
        int f = j / 96, k = j - f * 96;
        Wt2[j] = __float2half(W2[(size_t)k * 96 + f]);
    } else if (i < 128 * 96 + 96 * 96 + 96 * 32) {
        int j = i - 128 * 96 - 96 * 96;
        int f = j / 96, k = j - f * 96;
        Wt3[j] = __float2half(W3[(size_t)k * 32 + f]);
    }
}

__device__ inline int ld_idx(const int* ei, int half_, int i, int E, bool i64) {
    return i64 ? ei[2 * (half_ * (size_t)E + i)] : ei[half_ * (size_t)E + i];
}

// Phase A: partition edges into bins by dst>>7. Packed: (bin<<23)|(ln<<16)|src.
__global__ __launch_bounds__(256) void part_kernel(const int* __restrict__ ei,
                                                   const int* __restrict__ flags,
                                                   int* __restrict__ bin_cnt,
                                                   int* __restrict__ bins, int E, int n) {
    __shared__ int hist[NBINS_P], excl[NBINS_P], cur[NBINS_P], gpos[NBINS_P];
    __shared__ int tmp[256];
    __shared__ int stage[EPB];
    const int tid = threadIdx.x;
    const bool i64 = (flags[4] == 0);
    for (int b = tid; b < NBINS_P; b += 256) hist[b] = 0;
    __syncthreads();

    int v[EPB / 256];
    const int base = blockIdx.x * EPB;
#pragma unroll
    for (int j = 0; j < EPB / 256; j++) {
        int i = base + j * 256 + tid;
        v[j] = -1;
        if (i < E) {
            int s = ld_idx(ei, 0, i, E, i64);
            int d = ld_idx(ei, 1, i, E, i64);
            if ((unsigned)s < (unsigned)n && (unsigned)d < (unsigned)n) {
                int bin = d >> 7, ln = d & 127;
                v[j] = (bin << 23) | (ln << 16) | s;
                atomicAdd(&hist[bin], 1);
            }
        }
    }
    __syncthreads();
    int a0 = hist[2 * tid], a1 = hist[2 * tid + 1];
    int pairsum = a0 + a1;
    tmp[tid] = pairsum;
    __syncthreads();
    for (int off = 1; off < 256; off <<= 1) {
        int t = (tid >= off) ? tmp[tid - off] : 0;
        __syncthreads();
        tmp[tid] += t;
        __syncthreads();
    }
    int S = tmp[tid] - pairsum;
    excl[2 * tid] = S;
    excl[2 * tid + 1] = S + a0;
    cur[2 * tid] = S;
    cur[2 * tid + 1] = S + a0;
    __syncthreads();
    for (int b = tid; b < NBINS_P; b += 256)
        gpos[b] = hist[b] ? atomicAdd(&bin_cnt[b], hist[b]) : 0;
#pragma unroll
    for (int j = 0; j < EPB / 256; j++) {
        if (v[j] != -1) {
            int bin = ((unsigned)v[j]) >> 23;
            int p = atomicAdd(&cur[bin], 1);
            stage[p] = v[j];
        }
    }
    __syncthreads();
    int total = excl[NBINS_P - 1] + hist[NBINS_P - 1];
    for (int i = tid; i < total; i += 256) {
        int w = stage[i];
        int bin = ((unsigned)w) >> 23;
        int k = gpos[bin] + (i - excl[bin]);
        if (k < BCAP) bins[(size_t)bin * BCAP + k] = w;
    }
}

// Phase B: per-bin LDS CSR build (ushort slots), coalesced dump of csr + cnt.
__global__ __launch_bounds__(256) void build_kernel(const int* __restrict__ bin_cnt,
                                                    const int* __restrict__ bins,
                                                    int* __restrict__ cnt,
                                                    unsigned short* __restrict__ csr, int n) {
    __shared__ unsigned short lcsr[NPB * CAP];   // 16 KB
    __shared__ int lcnt[NPB];
    const int b = blockIdx.x, tid = threadIdx.x;
    for (int i = tid; i < NPB; i += 256) lcnt[i] = 0;
    __syncthreads();
    int m = min(bin_cnt[b], BCAP);
    for (int i = tid; i < m; i += 256) {
        int w = bins[(size_t)b * BCAP + i];
        int ln = (w >> 16) & 127;
        int p = atomicAdd(&lcnt[ln], 1);
        if (p < CAP) lcsr[ln * CAP + p] = (unsigned short)(w & 0xFFFF);
    }
    __syncthreads();
    const int node0 = b * NPB;
    const unsigned int* l32 = (const unsigned int*)lcsr;
    unsigned int* c32 = (unsigned int*)(csr + (size_t)node0 * CAP);
    for (int i = tid; i < NPB * CAP / 2; i += 256) {
        int node = node0 + (i >> 5);           // 32 uints per node row
        if (node < n) c32[i] = l32[i];
    }
    for (int t = tid; t < NPB; t += 256)
        if (node0 + t < n) cnt[node0 + t] = lcnt[t];
}

__device__ inline half8 to_h8(float4 u0, float4 u1) {
    half8 r;
    r[0] = (_Float16)u0.x; r[1] = (_Float16)u0.y; r[2] = (_Float16)u0.z; r[3] = (_Float16)u0.w;
    r[4] = (_Float16)u1.x; r[5] = (_Float16)u1.y; r[6] = (_Float16)u1.z; r[7] = (_Float16)u1.w;
    return r;
}

// out[n,f] = dinv[n] * sum_k X[n,k]*W[k,f].  OUT8: fp8 staging out, else fp16.
template <int K, int F, bool XF32, bool OUT8>
__global__ __launch_bounds__(256) void gemm_mfma(const void* __restrict__ X,
                                                 const __half* __restrict__ Wt,
                                                 const int* __restrict__ cnt,
                                                 void* __restrict__ out, int n) {
    constexpr int KP = K + 8;
    constexpr int FT = F / 16;
    constexpr int KC = K / 32;
    __shared__ _Float16 Wl[F * KP];
    for (int i = threadIdx.x; i < F * (K / 8); i += 256) {
        int f = i / (K / 8), c = i - f * (K / 8);
        *(half8*)&Wl[f * KP + c * 8] = *(const half8*)&Wt[(size_t)f * K + c * 8];
    }
    __syncthreads();
    const int wave = threadIdx.x >> 6, lane = threadIdx.x & 63;
    const int node0 = (blockIdx.x * 4 + wave) * 16;
    if (node0 >= n) return;
    const int m = lane & 15, q = lane >> 4;
    const int arow = min(node0 + m, n - 1);

    half8 af[KC];
    if (XF32) {
        const float* xp = (const float*)X + (size_t)arow * K + q * 8;
#pragma unroll
        for (int kc = 0; kc < KC; kc++) {
            float4 u0 = *(const float4*)(xp + kc * 32);
            float4 u1 = *(const float4*)(xp + kc * 32 + 4);
            af[kc] = to_h8(u0, u1);
        }
    } else {
        const __half* xp = (const __half*)X + (size_t)arow * K + q * 8;
#pragma unroll
        for (int kc = 0; kc < KC; kc++) af[kc] = *(const half8*)(xp + kc * 32);
    }

    f32x4 acc[FT];
#pragma unroll
    for (int t = 0; t < FT; t++) acc[t] = (f32x4)0.f;
#pragma unroll
    for (int kc = 0; kc < KC; kc++) {
#pragma unroll
        for (int t = 0; t < FT; t++) {
            half8 b = *(const half8*)&Wl[(t * 16 + m) * KP + kc * 32 + q * 8];
            acc[t] = __builtin_amdgcn_mfma_f32_16x16x32_f16(af[kc], b, acc[t], 0, 0, 0);
        }
    }
    float dv[4];
#pragma unroll
    for (int r = 0; r < 4; r++) {
        int node = node0 + q * 4 + r;
        dv[r] = (node < n) ? rsqrtf(1.0f + (float)cnt[node]) : 0.f;
    }
#pragma unroll
    for (int t = 0; t < FT; t++)
#pragma unroll
        for (int r = 0; r < 4; r++) {
            int node = node0 + q * 4 + r;
            if (node < n) {
                float vv = acc[t][r] * dv[r];
                if (OUT8)
                    ((unsigned char*)out)[(size_t)node * F + t * 16 + m] = f_to_fp8(vv);
                else
                    ((__half*)out)[(size_t)node * F + t * 16 + m] = __float2half(vv);
            }
        }
}

// agg F=96 over fp8 table (4.8MB, L2-resident). 2 edges/instr, preloaded idx
// pairs (8 independent gathers per 16-edge batch). lanes 0-23 edge A, 24-47
// edge B; shfl(+24) combine. Native fp8->f32 decode, f32 accumulate.
__global__ __launch_bounds__(256) void agg96_fp8(const unsigned char* __restrict__ xws,
                                                 const int* __restrict__ cnt,
                                                 const unsigned short* __restrict__ csr,
                                                 const float* __restrict__ bias,
                                                 __half* __restrict__ out, int n) {
    int node = blockIdx.x * 4 + (threadIdx.x >> 6);
    int lane = threadIdx.x & 63;
    if (node >= n) return;
    const int g = lane < 24 ? 0 : 1;
    const int c = g ? lane - 24 : lane;
    const bool act = lane < 48;
    int deg = cnt[node];
    int m = min(deg, CAP);
    float dv = rsqrtf(1.0f + (float)deg);
    const uint4* r4 = (const uint4*)(csr + (size_t)node * CAP);  // 128B-aligned
    const unsigned int* r2 = (const unsigned int*)r4;
    float4 a = {0.f, 0.f, 0.f, 0.f};
    if (lane < 24) {
        unsigned int w = *(const unsigned int*)(xws + (size_t)node * 96 + c * 4);
        a = fp8x4_to_f4(w);
    }
    int e = 0;
#define G96_U(pr_) (g ? ((pr_) >> 16) : ((pr_) & 0xFFFFu))
#define G96_LD(u_) (*(const unsigned int*)(xws + (size_t)(u_) * 96 + c * 4))
#define G96_ACC(w_) { float4 f_ = fp8x4_to_f4(w_); \
                      a.x += f_.x; a.y += f_.y; a.z += f_.z; a.w += f_.w; }
    for (; e + 16 <= m; e += 16) {
        uint4 pa = r4[e >> 3], pb = r4[(e >> 3) + 1];   // 2 idx loads, together
        if (act) {
            unsigned int w0 = G96_LD(G96_U(pa.x)), w1 = G96_LD(G96_U(pa.y));
            unsigned int w2 = G96_LD(G96_U(pa.z)), w3 = G96_LD(G96_U(pa.w));
            unsigned int w4 = G96_LD(G96_U(pb.x)), w5 = G96_LD(G96_U(pb.y));
            unsigned int w6 = G96_LD(G96_U(pb.z)), w7 = G96_LD(G96_U(pb.w));
            G96_ACC(w0) G96_ACC(w1) G96_ACC(w2) G96_ACC(w3)
            G96_ACC(w4) G96_ACC(w5) G96_ACC(w6) G96_ACC(w7)
        }
    }
    if (e + 8 <= m) {
        uint4 pa = r4[e >> 3];
        if (act) {
            unsigned int w0 = G96_LD(G96_U(pa.x)), w1 = G96_LD(G96_U(pa.y));
            unsigned int w2 = G96_LD(G96_U(pa.z)), w3 = G96_LD(G96_U(pa.w));
            G96_ACC(w0) G96_ACC(w1) G96_ACC(w2) G96_ACC(w3)
        }
        e += 8;
    }
    if (e + 4 <= m) {
        unsigned int p0 = r2[e >> 1], p1 = r2[(e >> 1) + 1];
        if (act) {
            unsigned int w0 = G96_LD(G96_U(p0)), w1 = G96_LD(G96_U(p1));
            G96_ACC(w0) G96_ACC(w1)
        }
        e += 4;
    }
    if (e + 2 <= m) {
        unsigned int p0 = r2[e >> 1];
        if (act) {
            unsigned int w0 = G96_LD(G96_U(p0));
            G96_ACC(w0)
        }
        e += 2;
    }
    if (e < m && lane < 24) {
        int u = ((const unsigned short*)r4)[e];
        G96_ACC(G96_LD(u))
    }
#undef G96_U
#undef G96_LD
#undef G96_ACC
    float px = __shfl(a.x, lane + 24);
    float py = __shfl(a.y, lane + 24);
    float pz = __shfl(a.z, lane + 24);
    float pw = __shfl(a.w, lane + 24);
    if (lane < 24) {
        a.x += px; a.y += py; a.z += pz; a.w += pw;
        float4 bb = *(const float4*)&bias[c * 4];
        float r0 = fmaxf(fmaf(dv, a.x, bb.x), 0.f);
        float r1 = fmaxf(fmaf(dv, a.y, bb.y), 0.f);
        float r2v = fmaxf(fmaf(dv, a.z, bb.z), 0.f);
        float r3 = fmaxf(fmaf(dv, a.w, bb.w), 0.f);
        union { __half2 h[2]; uint2 u; } pk;
        pk.h[0] = __floats2half2_rn(r0, r1);
        pk.h[1] = __floats2half2_rn(r2v, r3);
        *(uint2*)(out + (size_t)node * 96 + c * 4) = pk.u;
    }
}

// extract ushort index j (0..7) from a uint4 of 8 packed ushorts
__device__ inline int ext8(uint4 p, int j) {
    unsigned int h = (j & 4) ? ((j & 2) ? p.w : p.z) : ((j & 2) ? p.y : p.x);
    return (j & 1) ? (int)(h >> 16) : (int)(h & 0xFFFFu);
}

// agg F=32 (fp16 table, 3.2MB L2-fit) + log_softmax, preloaded indices,
// 4 edges/instr (4 x 16-lane groups), half2 packed accumulate; f32 out.
__global__ __launch_bounds__(256) void agg32_lsm(const __half* __restrict__ xws,
                                                 const int* __restrict__ cnt,
                                                 const unsigned short* __restrict__ csr,
                                                 const float* __restrict__ bias,
                                                 float* __restrict__ out, int n) {
    int node = blockIdx.x * 4 + (threadIdx.x >> 6);
    int lane = threadIdx.x & 63;
    if (node >= n) return;
    const int g = lane >> 4, l = lane & 15;
    int deg = cnt[node];
    int m = min(deg, CAP);
    float dv = rsqrtf(1.0f + (float)deg);
    const uint4* r4 = (const uint4*)(csr + (size_t)node * CAP);
    __half2 a = h2u(0u);
    if (g == 0) a = *(const __half2*)(xws + (size_t)node * 32 + l * 2);
    int e = 0;
    for (; e + 16 <= m; e += 16) {
        uint4 pa = r4[e >> 3], pb = r4[(e >> 3) + 1];
        int u0 = ext8(pa, g), u1 = ext8(pa, g + 4);
        int u2 = ext8(pb, g), u3 = ext8(pb, g + 4);
        __half2 f0 = *(const __half2*)(xws + (size_t)u0 * 32 + l * 2);
        __half2 f1 = *(const __half2*)(xws + (size_t)u1 * 32 + l * 2);
        __half2 f2 = *(const __half2*)(xws + (size_t)u2 * 32 + l * 2);
        __half2 f3 = *(const __half2*)(xws + (size_t)u3 * 32 + l * 2);
        a = __hadd2(a, __hadd2(__hadd2(f0, f1), __hadd2(f2, f3)));
    }
    if (e + 8 <= m) {
        uint4 pa = r4[e >> 3];
        int u0 = ext8(pa, g), u1 = ext8(pa, g + 4);
        __half2 f0 = *(const __half2*)(xws + (size_t)u0 * 32 + l * 2);
        __half2 f1 = *(const __half2*)(xws + (size_t)u1 * 32 + l * 2);
        a = __hadd2(a, __hadd2(f0, f1));
        e += 8;
    }
    if (e + 4 <= m) {
        unsigned int p0 = ((const unsigned int*)r4)[e >> 1];
        unsigned int p1 = ((const unsigned int*)r4)[(e >> 1) + 1];
        unsigned int h = (g & 2) ? p1 : p0;
        int u = (g & 1) ? (int)(h >> 16) : (int)(h & 0xFFFF);
        a = __hadd2(a, *(const __half2*)(xws + (size_t)u * 32 + l * 2));
        e += 4;
    }
    for (; e < m; e++) {
        if (g == 0) {
            int u = ((const unsigned short*)r4)[e];
            a = __hadd2(a, *(const __half2*)(xws + (size_t)u * 32 + l * 2));
        }
    }
    a = __hadd2(a, h2u((unsigned int)__shfl_xor((int)u_h2(a), 16)));
    a = __hadd2(a, h2u((unsigned int)__shfl_xor((int)u_h2(a), 32)));
    if (g == 0) {
        float2 av = __half22float2(a);
        float2 b = *(const float2*)&bias[l * 2];
        float rx = fmaf(dv, av.x, b.x), ry = fmaf(dv, av.y, b.y);
        float mx = fmaxf(rx, ry);
        mx = fmaxf(mx, __shfl_xor(mx, 1));
        mx = fmaxf(mx, __shfl_xor(mx, 2));
        mx = fmaxf(mx, __shfl_xor(mx, 4));
        mx = fmaxf(mx, __shfl_xor(mx, 8));
        float s = expf(rx - mx) + expf(ry - mx);
        s += __shfl_xor(s, 1);
        s += __shfl_xor(s, 2);
        s += __shfl_xor(s, 4);
        s += __shfl_xor(s, 8);
        float ls = logf(s);
        ((float2*)out)[(size_t)node * 16 + l] = {rx - mx - ls, ry - mx - ls};
    }
}

extern "C" void kernel_launch(void* const* d_in, const int* in_sizes, int n_in,
                              void* d_out, int out_size, void* d_ws, size_t ws_size,
                              hipStream_t stream) {
    const float* x  = (const float*)d_in[0];
    const int*   ei = (const int*)d_in[1];
    const float* W1 = (const float*)d_in[2];
    const float* b1 = (const float*)d_in[3];
    const float* W2 = (const float*)d_in[4];
    const float* b2 = (const float*)d_in[5];
    const float* W3 = (const float*)d_in[6];
    const float* b3 = (const float*)d_in[7];
    float* out = (float*)d_out;

    const int N_ = in_sizes[0] / 128;   // 50000
    const int E_ = in_sizes[1] / 2;     // 800000
    const int NBINS = (N_ + NPB - 1) / NPB;  // 391

    char* base = (char*)d_ws;
    size_t off = 0;
    auto take = [&](size_t bytes) {
        void* p = base + off;
        off = (off + bytes + 255) & ~(size_t)255;
        return p;
    };
    int*    flags   = (int*)take(4 * 8);
    int*    bin_cnt = (int*)take(4 * NBINS_P);
    int*    bins    = (int*)take(4 * (size_t)NBINS * BCAP);
    int*    cnt     = (int*)take(4 * (size_t)N_);
    unsigned short* csr = (unsigned short*)take(2 * (size_t)N_ * CAP);
    __half* Wt1     = (__half*)take(2 * 128 * 96);
    __half* Wt2     = (__half*)take(2 * 96 * 96);
    __half* Wt3     = (__half*)take(2 * 96 * 32);
    unsigned char* bufA = (unsigned char*)take(2 * (size_t)N_ * 96);  // fp8 / fp16 stage
    __half* bufB    = (__half*)take(2 * (size_t)N_ * 96);             // fp16 activations

    const int prepBlocks = 1 + (128 * 96 + 96 * 96 + 96 * 32 + 255) / 256;
    prep_kernel<<<prepBlocks, 256, 0, stream>>>(ei, in_sizes[1], flags, bin_cnt,
                                                W1, W2, W3, Wt1, Wt2, Wt3);
    part_kernel<<<(E_ + EPB - 1) / EPB, 256, 0, stream>>>(ei, flags, bin_cnt, bins, E_, N_);
    build_kernel<<<NBINS, 256, 0, stream>>>(bin_cnt, bins, cnt, csr, N_);

    const int gGemm = (N_ + 63) / 64;
    const int gAgg  = (N_ + 3) / 4;

    gemm_mfma<128, 96, true, true><<<gGemm, 256, 0, stream>>>(x, Wt1, cnt, bufA, N_);
    agg96_fp8<<<gAgg, 256, 0, stream>>>(bufA, cnt, csr, b1, bufB, N_);
    gemm_mfma<96, 96, false, true><<<gGemm, 256, 0, stream>>>(bufB, Wt2, cnt, bufA, N_);
    agg96_fp8<<<gAgg, 256, 0, stream>>>(bufA, cnt, csr, b2, bufB, N_);
    gemm_mfma<96, 32, false, false><<<gGemm, 256, 0, stream>>>(bufB, Wt3, cnt, bufA, N_);
    agg32_lsm<<<gAgg, 256, 0, stream>>>((const __half*)bufA, cnt, csr, b3, out, N_);
}